// Round 12
// baseline (32.405 us; speedup 1.0000x reference)
//
#include <hip/hip_runtime.h>
#include <hip/hip_bf16.h>
#include <math.h>

#define MAXP 32
#define PPW  8   // pillars per wave

typedef __attribute__((ext_vector_type(8)))  short bf16x8;
typedef __attribute__((ext_vector_type(16))) float f32x16;

template <int CTRL>
__device__ __forceinline__ float dppadd(float v) {
    int t = __builtin_amdgcn_update_dpp(0, __float_as_int(v), CTRL, 0xF, 0xF, false);
    return v + __int_as_float(t);
}
// sum within each 16-lane group (HW-verified R6-R10)
__device__ __forceinline__ float sum16(float v) {
    v = dppadd<0xB1>(v);    // xor1
    v = dppadd<0x4E>(v);    // xor2
    v = dppadd<0x141>(v);   // row_half_mirror
    v = dppadd<0x140>(v);   // row_mirror
    return v;
}
__device__ __forceinline__ float rdf(float v, int l) {
    return __int_as_float(__builtin_amdgcn_readlane(__float_as_int(v), l));
}
// 1-instruction bf16 pair pack (lo -> low16, hi -> high16); proven R10
__device__ __forceinline__ int cvtpk(float lo, float hi) {
    int r;
    asm("v_cvt_pk_bf16_f32 %0, %1, %2" : "=v"(r) : "v"(lo), "v"(hi));
    return r;
}
__device__ __forceinline__ float rmax16(f32x16 a) {   // R10's fmaxf tree
    float m1 = fmaxf(fmaxf(a[0], a[1]),  a[2]);
    float m2 = fmaxf(fmaxf(a[3], a[4]),  a[5]);
    float m3 = fmaxf(fmaxf(a[6], a[7]),  a[8]);
    float m4 = fmaxf(fmaxf(a[9], a[10]), a[11]);
    float m5 = fmaxf(fmaxf(a[12],a[13]), a[14]);
    float mm = fmaxf(fmaxf(m1, m2), m3);
    return fmaxf(fmaxf(fmaxf(m4, m5), a[15]), mm);
}

union FragAB { bf16x8 v; int i[4]; };

__global__ __launch_bounds__(256) void pfn_kernel(
    const float* __restrict__ voxels,
    const int*   __restrict__ num_points,
    const int*   __restrict__ coords,
    const float* __restrict__ W,
    const float* __restrict__ gammav,
    const float* __restrict__ betav,
    const float* __restrict__ rmean,
    const float* __restrict__ rvar,
    float*       __restrict__ out,
    int N)
{
    const int  lane = threadIdx.x & 63;
    const int  wid  = threadIdx.x >> 6;
    const int  pt   = lane & 31;          // A-frag row (point slot)
    const bool lo32 = (lane < 32);

    int vz;                               // opaque 0: pins small loads to VMEM
    asm("v_mov_b32 %0, 0" : "=v"(vz));

    const int base = (blockIdx.x * 4 + wid) * PPW;
    if (base >= N) return;

    // ---- per-lane channel coefficients for both halves (once per wave) ----
    const int cL = lane & 31, cH = cL + 32;
    float AL,BL,CLc,DLc,P4L,P5L,P6L,P7L,P8L,shL;
    float AH,BH,CHc,DHc,P4H,P5H,P6H,P7H,P8H,shH;
    {
        float w0=W[cL],w1=W[64+cL],w2=W[128+cL],w3=W[192+cL],w4=W[256+cL],
              w5=W[320+cL],w6=W[384+cL],w7=W[448+cL],w8=W[512+cL];
        float inv = gammav[cL] * rsqrtf(rvar[cL] + 1e-3f);
        shL = fmaf(-rmean[cL], inv, betav[cL]);
        AL=(w0+w4+w7)*inv; BL=(w1+w5+w8)*inv; CLc=(w2+w6)*inv; DLc=w3*inv;
        P4L=w4*inv; P5L=w5*inv; P6L=w6*inv; P7L=w7*inv; P8L=w8*inv;
    }
    {
        float w0=W[cH],w1=W[64+cH],w2=W[128+cH],w3=W[192+cH],w4=W[256+cH],
              w5=W[320+cH],w6=W[384+cH],w7=W[448+cH],w8=W[512+cH];
        float inv = gammav[cH] * rsqrtf(rvar[cH] + 1e-3f);
        shH = fmaf(-rmean[cH], inv, betav[cH]);
        AH=(w0+w4+w7)*inv; BH=(w1+w5+w8)*inv; CHc=(w2+w6)*inv; DHc=w3*inv;
        P4H=w4*inv; P5H=w5*inv; P6H=w6*inv; P7H=w7*inv; P8H=w8*inv;
    }

    // ---- B-frags: K-rows carry ALL linear terms (layout proven R10) ----
    // lanes 0-31  k=0..7:  (A, B, C, Dk, P4, P5, P6, -P7)
    // lanes 32-63 k=8..15: (-P8, shift, 0, ..., 0)
    FragAB fbL, fbH;
    if (lo32) {
        fbL.i[0]=cvtpk(AL,BL);   fbL.i[1]=cvtpk(CLc,DLc);
        fbL.i[2]=cvtpk(P4L,P5L); fbL.i[3]=cvtpk(P6L,-P7L);
        fbH.i[0]=cvtpk(AH,BH);   fbH.i[1]=cvtpk(CHc,DHc);
        fbH.i[2]=cvtpk(P4H,P5H); fbH.i[3]=cvtpk(P6H,-P7H);
    } else {
        fbL.i[0]=cvtpk(-P8L,shL); fbL.i[1]=0; fbL.i[2]=0; fbL.i[3]=0;
        fbH.i[0]=cvtpk(-P8H,shH); fbH.i[1]=0; fbH.i[2]=0; fbH.i[3]=0;
    }

    const f32x16 zacc = {0,0,0,0,0,0,0,0,0,0,0,0,0,0,0,0};

#define LOADP(G, NP, C0, C1, idx) do {                                         \
    const int s_ = min((idx), N - 1);                                          \
    G  = *(const float4*)((const char*)voxels +                                \
                          (size_t)s_ * 512 + (size_t)pt * 16);                 \
    NP = *(const int*)((const char*)num_points + (size_t)s_*4  + vz);          \
    C0 = *(const int*)((const char*)coords     + (size_t)s_*12 + vz);          \
    C1 = *(const int*)((const char*)coords     + (size_t)s_*12 + 4 + vz);      \
} while (0)

// R10 loop body, verbatim (proven: absmax 0.0625)
#define BODY(GC, NP, C0, C1, PC) do {                                          \
    float bx = sum16((GC).x), by = sum16((GC).y), bz = sum16((GC).z);          \
    bx += __shfl_xor(bx, 16);                                                  \
    by += __shfl_xor(by, 16);                                                  \
    bz += __shfl_xor(bz, 16);                                                  \
    const float rnp = __builtin_amdgcn_rcpf((float)(NP));                      \
    const float msx = -bx*rnp, msy = -by*rnp, msz = -bz*rnp;                   \
    const float cxf = fmaf((float)(C0), 0.2f, 0.1f);   /* VX/2 + 0    */       \
    const float cyf = fmaf((float)(C1), 0.2f, -25.5f); /* VY/2 - 25.6 */       \
    const bool  cv  = (pt < (NP));                                             \
    const float xs = cv ? (GC).x : rdf((GC).x, 0);                             \
    const float ys = cv ? (GC).y : rdf((GC).y, 0);                             \
    const float zs = cv ? (GC).z : rdf((GC).z, 0);                             \
    const float ws = cv ? (GC).w : rdf((GC).w, 0);                             \
    FragAB fa;                                                                 \
    fa.i[0] = lo32 ? cvtpk(xs, ys)   : cvtpk(cyf, 1.0f);                       \
    fa.i[1] = lo32 ? cvtpk(zs, ws)   : 0;                                      \
    fa.i[2] = lo32 ? cvtpk(msx, msy) : 0;                                      \
    fa.i[3] = lo32 ? cvtpk(msz, cxf) : 0;                                      \
    f32x16 accL = __builtin_amdgcn_mfma_f32_32x32x16_bf16(fa.v, fbL.v, zacc, 0, 0, 0); \
    f32x16 accH = __builtin_amdgcn_mfma_f32_32x32x16_bf16(fa.v, fbH.v, zacc, 0, 0, 0); \
    float mL = rmax16(accL);                                                   \
    float mH = rmax16(accH);                                                   \
    mL = fmaxf(mL, __shfl_xor(mL, 32));                                        \
    mH = fmaxf(mH, __shfl_xor(mH, 32));                                        \
    const bool pad = ((NP) < MAXP);                                            \
    mL = pad ? fmaxf(mL, shL) : mL;                                            \
    mH = pad ? fmaxf(mH, shH) : mH;                                            \
    const float o = fmaxf(lo32 ? mL : mH, 0.0f);                               \
    if ((PC) < N) out[(size_t)(PC) * 64 + lane] = o;                           \
} while (0)

    // ---- depth-2 software pipeline over PPW pillars (the ONE new thing) ----
    float4 gA, gB;
    int npA, c0A, c1A, npB, c0B, c1B;
    LOADP(gA, npA, c0A, c1A, base + 0);
    LOADP(gB, npB, c0B, c1B, base + 1);

    #pragma unroll 1
    for (int i = 0; i < PPW; i += 2) {
        const float4 gc = gA; const int np = npA, c0 = c0A, c1 = c1A;
        if (i + 2 < PPW) LOADP(gA, npA, c0A, c1A, base + i + 2);
        BODY(gc, np, c0, c1, base + i);

        const float4 gd = gB; const int nq = npB, e0 = c0B, e1 = c1B;
        if (i + 3 < PPW) LOADP(gB, npB, c0B, c1B, base + i + 3);
        BODY(gd, nq, e0, e1, base + i + 1);
    }
#undef BODY
#undef LOADP
}

extern "C" void kernel_launch(void* const* d_in, const int* in_sizes, int n_in,
                              void* d_out, int out_size, void* d_ws, size_t ws_size,
                              hipStream_t stream) {
    const float* voxels     = (const float*)d_in[0];
    const int*   num_points = (const int*)  d_in[1];
    const int*   coords     = (const int*)  d_in[2];
    const float* W          = (const float*)d_in[3];
    const float* gammav     = (const float*)d_in[4];
    const float* betav      = (const float*)d_in[5];
    const float* rmean      = (const float*)d_in[6];
    const float* rvar       = (const float*)d_in[7];
    float*       out        = (float*)d_out;

    const int N = in_sizes[1];                    // one entry per pillar
    const int per_block = 4 * PPW;                // 4 waves x PPW pillars
    const int blocks = (N + per_block - 1) / per_block;
    pfn_kernel<<<blocks, 256, 0, stream>>>(voxels, num_points, coords, W,
                                           gammav, betav, rmean, rvar, out, N);
}

// Round 13
// 31.856 us; speedup vs baseline: 1.0172x; 1.0172x over previous
//
#include <hip/hip_runtime.h>
#include <hip/hip_bf16.h>
#include <math.h>

#define MAXP 32
#define PPW  8   // pillars per wave

typedef __attribute__((ext_vector_type(8)))  short bf16x8;
typedef __attribute__((ext_vector_type(16))) float f32x16;

template <int CTRL>
__device__ __forceinline__ float dppadd(float v) {
    int t = __builtin_amdgcn_update_dpp(0, __float_as_int(v), CTRL, 0xF, 0xF, false);
    return v + __int_as_float(t);
}
// sum within each 16-lane group (HW-verified R6-R12)
__device__ __forceinline__ float sum16(float v) {
    v = dppadd<0xB1>(v);    // xor1
    v = dppadd<0x4E>(v);    // xor2
    v = dppadd<0x141>(v);   // row_half_mirror
    v = dppadd<0x140>(v);   // row_mirror
    return v;
}
// full 32-sum from 16-group sums; direction-agnostic (duplicated inputs)
__device__ __forceinline__ float fold16(float s) {
    auto pr = __builtin_amdgcn_permlane16_swap(__float_as_uint(s),
                                               __float_as_uint(s), false, false);
    return __uint_as_float(pr[0]) + __uint_as_float(pr[1]);
}
// 1-instruction bf16 pair pack (lo -> low16, hi -> high16); proven R10
__device__ __forceinline__ int cvtpk(float lo, float hi) {
    int r;
    asm("v_cvt_pk_bf16_f32 %0, %1, %2" : "=v"(r) : "v"(lo), "v"(hi));
    return r;
}
__device__ __forceinline__ float rmax16(f32x16 a) {   // max3-fusable tree
    float m1 = fmaxf(fmaxf(a[0], a[1]),  a[2]);
    float m2 = fmaxf(fmaxf(a[3], a[4]),  a[5]);
    float m3 = fmaxf(fmaxf(a[6], a[7]),  a[8]);
    float m4 = fmaxf(fmaxf(a[9], a[10]), a[11]);
    float m5 = fmaxf(fmaxf(a[12],a[13]), a[14]);
    float mm = fmaxf(fmaxf(m1, m2), m3);
    return fmaxf(fmaxf(fmaxf(m4, m5), a[15]), mm);
}

union FragAB { bf16x8 v; int i[4]; };

__global__ __launch_bounds__(256) void pfn_kernel(
    const float* __restrict__ voxels,
    const int*   __restrict__ num_points,
    const int*   __restrict__ coords,
    const float* __restrict__ W,
    const float* __restrict__ gammav,
    const float* __restrict__ betav,
    const float* __restrict__ rmean,
    const float* __restrict__ rvar,
    float*       __restrict__ out,
    int N)
{
    const int  lane = threadIdx.x & 63;
    const int  wid  = threadIdx.x >> 6;
    const int  pt   = lane & 31;          // A-frag row (point slot)
    const bool lo32 = (lane < 32);

    int vz;                               // opaque 0: pins small loads to VMEM
    asm("v_mov_b32 %0, 0" : "=v"(vz));

    const int base = (blockIdx.x * 4 + wid) * PPW;
    if (base >= N) return;

    // ---- per-lane channel coefficients for both halves (once per wave) ----
    const int cL = lane & 31, cH = cL + 32;
    float AL,BL,CLc,DLc,P4L,P5L,P6L,P7L,P8L,shL;
    float AH,BH,CHc,DHc,P4H,P5H,P6H,P7H,P8H,shH;
    {
        float w0=W[cL],w1=W[64+cL],w2=W[128+cL],w3=W[192+cL],w4=W[256+cL],
              w5=W[320+cL],w6=W[384+cL],w7=W[448+cL],w8=W[512+cL];
        float inv = gammav[cL] * rsqrtf(rvar[cL] + 1e-3f);
        shL = fmaf(-rmean[cL], inv, betav[cL]);
        AL=(w0+w4+w7)*inv; BL=(w1+w5+w8)*inv; CLc=(w2+w6)*inv; DLc=w3*inv;
        P4L=w4*inv; P5L=w5*inv; P6L=w6*inv; P7L=w7*inv; P8L=w8*inv;
    }
    {
        float w0=W[cH],w1=W[64+cH],w2=W[128+cH],w3=W[192+cH],w4=W[256+cH],
              w5=W[320+cH],w6=W[384+cH],w7=W[448+cH],w8=W[512+cH];
        float inv = gammav[cH] * rsqrtf(rvar[cH] + 1e-3f);
        shH = fmaf(-rmean[cH], inv, betav[cH]);
        AH=(w0+w4+w7)*inv; BH=(w1+w5+w8)*inv; CHc=(w2+w6)*inv; DHc=w3*inv;
        P4H=w4*inv; P5H=w5*inv; P6H=w6*inv; P7H=w7*inv; P8H=w8*inv;
    }
    const float shSel = lo32 ? shL : shH;  // padded-point value for MY channel

    // ---- B-frags: K-rows carry ALL linear terms (layout proven R10) ----
    // lanes 0-31  k=0..7:  (A, B, C, Dk, P4, P5, P6, -P7)
    // lanes 32-63 k=8..15: (-P8, shift, 0, ..., 0)
    FragAB fbL, fbH;
    if (lo32) {
        fbL.i[0]=cvtpk(AL,BL);   fbL.i[1]=cvtpk(CLc,DLc);
        fbL.i[2]=cvtpk(P4L,P5L); fbL.i[3]=cvtpk(P6L,-P7L);
        fbH.i[0]=cvtpk(AH,BH);   fbH.i[1]=cvtpk(CHc,DHc);
        fbH.i[2]=cvtpk(P4H,P5H); fbH.i[3]=cvtpk(P6H,-P7H);
    } else {
        fbL.i[0]=cvtpk(-P8L,shL); fbL.i[1]=0; fbL.i[2]=0; fbL.i[3]=0;
        fbH.i[0]=cvtpk(-P8H,shH); fbH.i[1]=0; fbH.i[2]=0; fbH.i[3]=0;
    }

    const f32x16 zacc = {0,0,0,0,0,0,0,0,0,0,0,0,0,0,0,0};

#define LOADP(G, NP, C0, C1, idx) do {                                         \
    const int s_ = min((idx), N - 1);                                          \
    G  = *(const float4*)((const char*)voxels +                                \
                          (size_t)s_ * 512 + (size_t)pt * 16);                 \
    NP = *(const int*)((const char*)num_points + (size_t)s_*4  + vz);          \
    C0 = *(const int*)((const char*)coords     + (size_t)s_*12 + vz);          \
    C1 = *(const int*)((const char*)coords     + (size_t)s_*12 + 4 + vz);      \
} while (0)

// R10 body with zero-DS cross-lane ops (permlane16/32_swap, pack-then-select)
#define BODY(GC, NP, C0, C1, PC) do {                                          \
    const float bx = fold16(sum16((GC).x));                                    \
    const float by = fold16(sum16((GC).y));                                    \
    const float bz = fold16(sum16((GC).z));                                    \
    const float rnp = __builtin_amdgcn_rcpf((float)(NP));                      \
    const float msx = -bx*rnp, msy = -by*rnp, msz = -bz*rnp;                   \
    const float cxf = fmaf((float)(C0), 0.2f, 0.1f);   /* VX/2 + 0    */       \
    const float cyf = fmaf((float)(C1), 0.2f, -25.5f); /* VY/2 - 25.6 */       \
    const int  p0 = cvtpk((GC).x, (GC).y);                                     \
    const int  p1 = cvtpk((GC).z, (GC).w);                                     \
    const int  q0 = __builtin_amdgcn_readlane(p0, 0);                          \
    const int  q1 = __builtin_amdgcn_readlane(p1, 0);                          \
    const bool cv = (pt < (NP));                                               \
    FragAB fa;                                                                 \
    fa.i[0] = lo32 ? (cv ? p0 : q0) : cvtpk(cyf, 1.0f);                        \
    fa.i[1] = lo32 ? (cv ? p1 : q1) : 0;                                       \
    fa.i[2] = lo32 ? cvtpk(msx, msy) : 0;                                      \
    fa.i[3] = lo32 ? cvtpk(msz, cxf) : 0;                                      \
    f32x16 accL = __builtin_amdgcn_mfma_f32_32x32x16_bf16(fa.v, fbL.v, zacc, 0, 0, 0); \
    f32x16 accH = __builtin_amdgcn_mfma_f32_32x32x16_bf16(fa.v, fbH.v, zacc, 0, 0, 0); \
    const float mL = rmax16(accL);                                             \
    const float mH = rmax16(accH);                                             \
    /* direction-agnostic cross-half merge via double permlane32_swap */       \
    auto pm = __builtin_amdgcn_permlane32_swap(__float_as_uint(mL),            \
                                               __float_as_uint(mH), false, false); \
    const float mr = fmaxf(__uint_as_float(pm[0]), __uint_as_float(pm[1]));    \
    auto pz = __builtin_amdgcn_permlane32_swap(__float_as_uint(mr),            \
                                               __float_as_uint(mr), false, false); \
    float z = lo32 ? __uint_as_float(pz[0]) : __uint_as_float(pz[1]);          \
    z = ((NP) < MAXP) ? fmaxf(z, shSel) : z;  /* padded pts contribute shift */\
    if ((PC) < N) out[(size_t)(PC) * 64 + lane] = fmaxf(z, 0.0f);              \
} while (0)

    // ---- depth-2 software pipeline over PPW pillars (proven R12) ----
    float4 gA, gB;
    int npA, c0A, c1A, npB, c0B, c1B;
    LOADP(gA, npA, c0A, c1A, base + 0);
    LOADP(gB, npB, c0B, c1B, base + 1);

    #pragma unroll 1
    for (int i = 0; i < PPW; i += 2) {
        const float4 gc = gA; const int np = npA, c0 = c0A, c1 = c1A;
        if (i + 2 < PPW) LOADP(gA, npA, c0A, c1A, base + i + 2);
        BODY(gc, np, c0, c1, base + i);

        const float4 gd = gB; const int nq = npB, e0 = c0B, e1 = c1B;
        if (i + 3 < PPW) LOADP(gB, npB, c0B, c1B, base + i + 3);
        BODY(gd, nq, e0, e1, base + i + 1);
    }
#undef BODY
#undef LOADP
}

extern "C" void kernel_launch(void* const* d_in, const int* in_sizes, int n_in,
                              void* d_out, int out_size, void* d_ws, size_t ws_size,
                              hipStream_t stream) {
    const float* voxels     = (const float*)d_in[0];
    const int*   num_points = (const int*)  d_in[1];
    const int*   coords     = (const int*)  d_in[2];
    const float* W          = (const float*)d_in[3];
    const float* gammav     = (const float*)d_in[4];
    const float* betav      = (const float*)d_in[5];
    const float* rmean      = (const float*)d_in[6];
    const float* rvar       = (const float*)d_in[7];
    float*       out        = (float*)d_out;

    const int N = in_sizes[1];                    // one entry per pillar
    const int per_block = 4 * PPW;                // 4 waves x PPW pillars
    const int blocks = (N + per_block - 1) / per_block;
    pfn_kernel<<<blocks, 256, 0, stream>>>(voxels, num_points, coords, W,
                                           gammav, betav, rmean, rvar, out, N);
}